// Round 13
// baseline (503.337 us; speedup 1.0000x reference)
//
#include <hip/hip_runtime.h>
#include <hip/hip_bf16.h>

typedef unsigned short u16;
typedef unsigned int u32;
typedef unsigned long long u64;
typedef float f32x4 __attribute__((ext_vector_type(4)));
typedef u16 u16x4 __attribute__((ext_vector_type(4)));
typedef u16 u16x8 __attribute__((ext_vector_type(8)));
typedef short s16x8 __attribute__((ext_vector_type(8)));

// ---------- helpers ----------
__device__ __forceinline__ u16 f2b(float f) {
  return __builtin_bit_cast(u16, __float2bfloat16(f));
}
__device__ __forceinline__ float b2f(u16 u) {
  return __builtin_bit_cast(float, ((u32)u) << 16);
}
__device__ __forceinline__ f32x4 ldb4(const u16* __restrict__ p) {
  u16x4 v = *(const u16x4*)p;
  f32x4 r;
#pragma unroll
  for (int i = 0; i < 4; ++i) r[i] = b2f(v[i]);
  return r;
}
__device__ __forceinline__ u16x4 cvt4(f32x4 v) {
  u16x4 r;
#pragma unroll
  for (int i = 0; i < 4; ++i) r[i] = f2b(v[i]);
  return r;
}
__device__ __forceinline__ f32x4 sigm4(f32x4 x) {
  f32x4 r;
#pragma unroll
  for (int i = 0; i < 4; ++i) r[i] = 1.0f / (1.0f + __expf(-x[i]));
  return r;
}
__device__ __forceinline__ f32x4 tanh4(f32x4 x) {
  f32x4 r;
#pragma unroll
  for (int i = 0; i < 4; ++i) {
    float xx = fminf(fmaxf(x[i], -15.0f), 15.0f);
    float e = __expf(2.0f * xx);
    r[i] = (e - 1.0f) / (e + 1.0f);
  }
  return r;
}

__device__ __forceinline__ void gload_lds16(const void* g, void* l) {
  typedef __attribute__((address_space(1))) const u32 gq_t;
  typedef __attribute__((address_space(3))) u32 lq_t;
  gq_t* gp = (gq_t*)(u64)(size_t)g;
  lq_t* lp = (lq_t*)(u32)(size_t)l;
  __builtin_amdgcn_global_load_lds(gp, lp, 16, 0, 0);
}

__device__ __forceinline__ f32x4 mfma_b(u16x8 a, u16x8 b, f32x4 c) {
  return __builtin_amdgcn_mfma_f32_16x16x32_bf16(
      __builtin_bit_cast(s16x8, a), __builtin_bit_cast(s16x8, b), c, 0, 0, 0);
}

// ---------- kernel 1: idx — flags + compact merged (single block) ----------
// updated[b][j] = (exists l: idd[b][l]==j) && j!=0 ; cidx = compact index of
// updated rows; mc[0] = count. Thread t owns scan elements t*16..t*16+15,
// which all lie in batch b = t>>5 (16 | 512).
__global__ __launch_bounds__(1024) void idx_kernel(
    const int* __restrict__ idd, int* __restrict__ updated,
    int* __restrict__ cidx, int* __restrict__ mc) {
  __shared__ int sf[512];
  __shared__ int sc[1024];
  const int t = threadIdx.x;
  const int myb = t >> 5;
  int fl[16];

  for (int bb = 0; bb < 32; ++bb) {
    if (t < 512) sf[t] = 0;
    __syncthreads();
    if (t < 512) sf[idd[(size_t)bb * 512 + t]] = 1;
    __syncthreads();
    if (myb == bb) {
#pragma unroll
      for (int i = 0; i < 16; ++i) {
        const int l = (t & 31) * 16 + i;
        fl[i] = (l != 0) ? sf[l] : 0;
      }
    }
    __syncthreads();
  }

  int cl = 0;
#pragma unroll
  for (int i = 0; i < 16; ++i) cl += fl[i];
  sc[t] = cl;
  __syncthreads();
  for (int d = 1; d < 1024; d <<= 1) {
    int v = sc[t];
    int add = (t >= d) ? sc[t - d] : 0;
    __syncthreads();
    sc[t] = v + add;
    __syncthreads();
  }
  int pos = sc[t] - cl;  // exclusive prefix
#pragma unroll
  for (int i = 0; i < 16; ++i) {
    updated[t * 16 + i] = fl[i];
    if (fl[i]) cidx[t * 16 + i] = pos++;
  }
  if (t == 1023) mc[0] = sc[1023];
}

// ---------- kernel 2: prep ----------
// Always: AF[grow][3072] = [bf16(x[d]) | bf16(h0[dr]) | bf16(h0[dl])].
// If updated: Ac[cidx[grow]][3072] = [bf16(x[grow]) | HR | HL] (compacted),
// where HR/HL are the dr/dl scatter-aggregates of h0 rows.
__global__ __launch_bounds__(256) void prep_kernel(
    const float* __restrict__ x, const float* __restrict__ h0,
    const int* __restrict__ idd, const int* __restrict__ idr,
    const int* __restrict__ idl, const int* __restrict__ updated,
    const int* __restrict__ cidx, u16* __restrict__ AF, u16* __restrict__ Ac) {
  __shared__ int listR[512], listL[512];
  __shared__ int cnt[2];
  const int j = blockIdx.x;
  const int b = blockIdx.y;
  const int tid = threadIdx.x;
  const int lane = tid & 63;
  const int wave = tid >> 6;
  const size_t grow = (size_t)b * 512 + j;
  const size_t bbase = (size_t)b * 512;
  const int k = tid * 4;

  // AF gather (every row)
  const int dd = idd[grow], rr = idr[grow], ll = idl[grow];
  u16* ar = AF + grow * 3072;
  *(u16x4*)(ar + k) = cvt4(*(const f32x4*)(x + (bbase + dd) * 1024 + k));
  *(u16x4*)(ar + 1024 + k) =
      cvt4(*(const f32x4*)(h0 + (bbase + rr) * 1024 + k));
  *(u16x4*)(ar + 2048 + k) =
      cvt4(*(const f32x4*)(h0 + (bbase + ll) * 1024 + k));

  if (!updated[grow]) return;  // block-uniform

  if (wave == 1 || wave == 2) {
    const int* ids = (wave == 1 ? idr : idl) + bbase;
    int* lst = (wave == 1 ? listR : listL);
    int base = 0;
#pragma unroll
    for (int c2 = 0; c2 < 8; ++c2) {
      int l = c2 * 64 + lane;
      int id = ids[l];
      u64 m = __ballot(id == j);
      if (id == j) {
        int pos = __popcll(m & ((1ull << lane) - 1ull));
        lst[base + pos] = l;
      }
      base += __popcll(m);
    }
    if (lane == 0) cnt[wave - 1] = base;
  }
  __syncthreads();

  u16* cr = Ac + (size_t)cidx[grow] * 3072;
  *(u16x4*)(cr + k) = cvt4(*(const f32x4*)(x + grow * 1024 + k));

  f32x4 sr = {0.f, 0.f, 0.f, 0.f};
  for (int t = 0; t < cnt[0]; ++t)
    sr += *(const f32x4*)(h0 + (bbase + listR[t]) * 1024 + k);
  *(u16x4*)(cr + 1024 + k) = cvt4(sr);

  f32x4 sl = {0.f, 0.f, 0.f, 0.f};
  for (int t = 0; t < cnt[1]; ++t)
    sl += *(const f32x4*)(h0 + (bbase + listL[t]) * 1024 + k);
  *(u16x4*)(cr + 2048 + k) = cvt4(sl);
}

// ---------- kernel 3: pack weights: WIOUT[3072][3072], WFT[1024][3072] -----
__global__ __launch_bounds__(256) void packw_kernel(
    const float* __restrict__ W_ioux, const float* __restrict__ W_iouh_r,
    const float* __restrict__ W_iouh_l, const float* __restrict__ W_fx,
    const float* __restrict__ W_fh0, const float* __restrict__ W_fh1,
    const float* __restrict__ W_fh2, const float* __restrict__ W_fh3,
    u16* __restrict__ WIOUT, u16* __restrict__ WFT) {
  const int t = blockIdx.x * 256 + threadIdx.x;
  const int NIOU = 3072 * 384;
  float v[8];
  if (t < NIOU) {
    const int n = t % 3072;
    const int k0 = (t / 3072) * 8;
    if (k0 < 1024) {
#pragma unroll
      for (int i = 0; i < 8; ++i) v[i] = W_ioux[(size_t)(k0 + i) * 3072 + n];
    } else if (k0 < 2048) {
#pragma unroll
      for (int i = 0; i < 8; ++i) v[i] = W_iouh_r[(size_t)(k0 - 1024 + i) * 3072 + n];
    } else {
#pragma unroll
      for (int i = 0; i < 8; ++i) v[i] = W_iouh_l[(size_t)(k0 - 2048 + i) * 3072 + n];
    }
    u16x8 o;
#pragma unroll
    for (int i = 0; i < 8; ++i) o[i] = f2b(v[i]);
    *(u16x8*)(WIOUT + (size_t)n * 3072 + k0) = o;
  } else {
    const int u = t - NIOU;
    const int n = u & 1023;
    const int k0 = (u >> 10) * 8;
    if (k0 < 1024) {
#pragma unroll
      for (int i = 0; i < 8; ++i) v[i] = W_fx[(size_t)(k0 + i) * 1024 + n];
    } else if (k0 < 2048) {
#pragma unroll
      for (int i = 0; i < 8; ++i)
        v[i] = W_fh0[(size_t)(k0 - 1024 + i) * 1024 + n] +
               W_fh1[(size_t)(k0 - 1024 + i) * 1024 + n];
    } else {
#pragma unroll
      for (int i = 0; i < 8; ++i)
        v[i] = W_fh2[(size_t)(k0 - 2048 + i) * 1024 + n] +
               W_fh3[(size_t)(k0 - 2048 + i) * 1024 + n];
    }
    u16x8 o;
#pragma unroll
    for (int i = 0; i < 8; ++i) o[i] = f2b(v[i]);
    *(u16x8*)(WFT + (size_t)n * 3072 + k0) = o;
  }
}

// ---------- kernel 4: merged 256x256 NT GEMM (champion schedule) -----------
// Grid 1024: bid<256 -> F role (AF @ WFT^T + b_fx -> F, N=1024);
// else IOU role (Ac @ WIOUT^T + b_ioux -> IOUc compact rows, N=3072,
// early-exit past McPad). A and B strides are 3072 for both -> one code path.
#define BARRIER __builtin_amdgcn_s_barrier()
#define VMCNT(n) asm volatile("s_waitcnt vmcnt(" #n ")")

__global__ __launch_bounds__(512, 2) void gemm_m(
    const u16* __restrict__ AF, const u16* __restrict__ WFT,
    u16* __restrict__ F, const float* __restrict__ bfx,
    const u16* __restrict__ Ac, const u16* __restrict__ WIOUT,
    u16* __restrict__ IOUc, const float* __restrict__ biou,
    const int* __restrict__ mc) {
  const int nk = 48;  // K = 3072
  __shared__ u16 lds_u16[65536];  // 128 KB: A 2x32KB @0, B 2x32KB @65536
  char* ldsb = (char*)lds_u16;
  const int tid = threadIdx.x;
  const int lane = tid & 63;
  const int wave = tid >> 6;
  const int wm = wave >> 2, wn = wave & 3;

  const int bid = blockIdx.x;
  const bool isF = bid < 256;
  const int lb = isF ? bid : bid - 256;
  const int nwg = isF ? 256 : 768;
  const int nbn = isF ? 4 : 12;
  const int swz = (lb & 7) * (nwg >> 3) + (lb >> 3);
  const int bm = swz / nbn, bn = swz % nbn;

  if (!isF) {
    const int McPad = (mc[0] + 255) & ~255;
    if (bm * 256 >= McPad) return;
  }

  const int N = isF ? 1024 : 3072;
  const u16* Abase = isF ? AF : Ac;
  const u16* Bt = isF ? WFT : WIOUT;
  u16* C = isF ? F : IOUc;
  const float* bias = isF ? bfx : biou;

  // staging source: inverse-XOR-swizzled so swizzled ds_reads see linear data
  const int srow = tid >> 3;
  const int ssw = (((tid & 7) * 16) ^ ((srow & 7) << 4)) >> 1;
  const u16* Ab = Abase + (size_t)(bm * 256 + srow) * 3072 + ssw;
  const u16* Bb = Bt + (size_t)(bn * 256 + srow) * 3072 + ssw;

#define SAg(PB, c, kt)                                                \
  gload_lds16(Ab + (size_t)(c) * 64 * 3072 + (size_t)(kt) * 64,       \
              ldsb + (PB) + (c) * 8192 + tid * 16)
#define SBg(PB, c, kt)                                                \
  gload_lds16(Bb + (size_t)(c) * 64 * 3072 + (size_t)(kt) * 64,       \
              ldsb + 65536 + (PB) + (c) * 8192 + tid * 16)

  // fragment read offsets (XOR swizzle depends only on lane)
  const int lb15 = lane & 15;
  const int lh16 = (lane >> 4) * 16;
  const int sw = (lane & 7) << 4;
  int a_off[2], b_off[2];
  a_off[0] = (wm * 64 + lb15) * 128 + (lh16 ^ sw);
  a_off[1] = (wm * 64 + lb15) * 128 + ((64 + lh16) ^ sw);
  b_off[0] = 65536 + (wn * 32 + lb15) * 128 + (lh16 ^ sw);
  b_off[1] = 65536 + (wn * 32 + lb15) * 128 + ((64 + lh16) ^ sw);

#define LDA(AR, PB, MS)                                                    \
  _Pragma("unroll") for (int fm = 0; fm < 4; ++fm) _Pragma("unroll")       \
      for (int kk = 0; kk < 2; ++kk) AR[fm][kk] =                          \
          *(const u16x8*)(ldsb + (PB) + a_off[kk] + (MS)*16384 + fm * 2048)
#define LDB(BR, PB, NS)                                                    \
  _Pragma("unroll") for (int fn = 0; fn < 2; ++fn) _Pragma("unroll")       \
      for (int kk = 0; kk < 2; ++kk) BR[fn][kk] =                          \
          *(const u16x8*)(ldsb + (PB) + b_off[kk] + (NS)*16384 + fn * 2048)
#define MFMAQ(MS, NS, AR, BR)                                              \
  _Pragma("unroll") for (int kk = 0; kk < 2; ++kk) _Pragma("unroll")       \
      for (int fm = 0; fm < 4; ++fm) _Pragma("unroll")                     \
      for (int fn = 0; fn < 2; ++fn) acc[MS][fm][NS][fn] =                 \
          mfma_b(AR[fm][kk], BR[fn][kk], acc[MS][fm][NS][fn])

  u16x8 ar0[4][2], ar1[4][2], br0[2][2], br1[2][2];
  f32x4 acc[2][4][2][2] = {};

  // prologue: tile0 all 8 chunks -> buf0; tile1's A01,B23 -> buf1
  SAg(0, 0, 0); SAg(0, 1, 0); SAg(0, 2, 0); SAg(0, 3, 0);
  SBg(0, 0, 0); SBg(0, 1, 0); SBg(0, 2, 0); SBg(0, 3, 0);
  SAg(32768, 0, 1); SAg(32768, 1, 1);
  SBg(32768, 2, 1); SBg(32768, 3, 1);
  VMCNT(4);
  BARRIER;

#define TILEBODY(PB, QB, Tcur)                                          \
  {                                                                     \
    const int s1 = ((Tcur) + 1 < nk) ? (Tcur) + 1 : nk - 1;             \
    const int s2 = ((Tcur) + 2 < nk) ? (Tcur) + 2 : nk - 1;             \
    SAg(QB, 2, s1); SAg(QB, 3, s1);                                     \
    LDB(br0, PB, 0);                                                    \
    LDA(ar0, PB, 0);                                                    \
    __builtin_amdgcn_s_setprio(1);                                      \
    MFMAQ(0, 0, ar0, br0);                                              \
    __builtin_amdgcn_s_setprio(0);                                      \
    BARRIER;                                                            \
    SBg(QB, 0, s1); SBg(QB, 1, s1);                                     \
    LDB(br1, PB, 1);                                                    \
    __builtin_amdgcn_s_setprio(1);                                      \
    MFMAQ(0, 1, ar0, br1);                                              \
    __builtin_amdgcn_s_setprio(0);                                      \
    BARRIER;                                                            \
    SAg(PB, 0, s2); SAg(PB, 1, s2);                                     \
    LDA(ar1, PB, 1);                                                    \
    __builtin_amdgcn_s_setprio(1);                                      \
    MFMAQ(1, 1, ar1, br1);                                              \
    __builtin_amdgcn_s_setprio(0);                                      \
    BARRIER;                                                            \
    SBg(PB, 2, s2); SBg(PB, 3, s2);                                     \
    __builtin_amdgcn_s_setprio(1);                                      \
    MFMAQ(1, 0, ar1, br0);                                              \
    __builtin_amdgcn_s_setprio(0);                                      \
    VMCNT(4);                                                           \
    BARRIER;                                                            \
  }

  for (int T = 0; T < nk; T += 2) {
    TILEBODY(0, 32768, T);
    TILEBODY(32768, 0, T + 1);
  }
  VMCNT(0);

  // epilogue
#pragma unroll
  for (int ms = 0; ms < 2; ++ms)
#pragma unroll
    for (int fm = 0; fm < 4; ++fm) {
      const int row0 = bm * 256 + ms * 128 + wm * 64 + fm * 16 + ((lane >> 4) * 4);
#pragma unroll
      for (int ns = 0; ns < 2; ++ns)
#pragma unroll
        for (int fn = 0; fn < 2; ++fn) {
          const int col = bn * 256 + ns * 128 + wn * 32 + fn * 16 + lb15;
          const float bv = bias[col];
#pragma unroll
          for (int r = 0; r < 4; ++r)
            C[(size_t)(row0 + r) * N + col] = f2b(acc[ms][fm][ns][fn][r] + bv);
        }
    }
#undef SAg
#undef SBg
#undef LDA
#undef LDB
#undef MFMAQ
#undef TILEBODY
}

// ---------- kernel 5: epilogue — gates + fc scatter (D-list only) ----------
__global__ __launch_bounds__(256) void epi_kernel(
    const u16* __restrict__ IOUc, const u16* __restrict__ F,
    const float* __restrict__ h0, const float* __restrict__ c0,
    const int* __restrict__ idd, const int* __restrict__ updated,
    const int* __restrict__ cidx, float* __restrict__ outh,
    float* __restrict__ outc) {
  __shared__ int listD[512];
  __shared__ int cnt0;
  const int j = blockIdx.x;
  const int b = blockIdx.y;
  const int tid = threadIdx.x;
  const int lane = tid & 63;
  const int wave = tid >> 6;
  const size_t grow = (size_t)b * 512 + j;
  const int k = tid * 4;

  if (!updated[grow]) {  // not updated: pass through (no ballot needed)
    f32x4 hv = *(const f32x4*)(h0 + grow * 1024 + k);
    f32x4 cv = *(const f32x4*)(c0 + grow * 1024 + k);
    *(f32x4*)(outh + grow * 1024 + k) = hv;
    *(f32x4*)(outc + grow * 1024 + k) = cv;
    return;
  }

  if (wave == 0) {
    const int* ids = idd + (size_t)b * 512;
    int base = 0;
#pragma unroll
    for (int c2 = 0; c2 < 8; ++c2) {
      int l = c2 * 64 + lane;
      int id = ids[l];
      u64 m = __ballot(id == j);
      if (id == j) {
        int pos = __popcll(m & ((1ull << lane) - 1ull));
        listD[base + pos] = l;
      }
      base += __popcll(m);
    }
    if (lane == 0) cnt0 = base;
  }
  __syncthreads();

  const int nD = cnt0;
  const u16* io = IOUc + (size_t)cidx[grow] * 3072;
  f32x4 gi = sigm4(ldb4(io + k));
  f32x4 go = sigm4(ldb4(io + 1024 + k));
  f32x4 gu = tanh4(ldb4(io + 2048 + k));
  f32x4 c = gi * gu;
  for (int t = 0; t < nD; ++t) {
    const size_t crow = (size_t)b * 512 + listD[t];
    f32x4 fg = sigm4(ldb4(F + crow * 1024 + k));  // b_fx folded in GEMM
    f32x4 cc = *(const f32x4*)(c0 + crow * 1024 + k);
    c += fg * cc;
  }
  f32x4 h = go * tanh4(c);
  *(f32x4*)(outh + grow * 1024 + k) = h;
  *(f32x4*)(outc + grow * 1024 + k) = c;
}

// ---------- host ----------
extern "C" void kernel_launch(void* const* d_in, const int* in_sizes, int n_in,
                              void* d_out, int out_size, void* d_ws,
                              size_t ws_size, hipStream_t stream) {
  const float* x = (const float*)d_in[0];
  const float* h0 = (const float*)d_in[1];
  const float* c0 = (const float*)d_in[2];
  const float* W_ioux = (const float*)d_in[3];
  const float* b_ioux = (const float*)d_in[4];
  const float* W_iouh_r = (const float*)d_in[5];
  const float* W_iouh_l = (const float*)d_in[6];
  const float* W_fx = (const float*)d_in[7];
  const float* b_fx = (const float*)d_in[8];
  const float* W_fh0 = (const float*)d_in[9];
  const float* W_fh1 = (const float*)d_in[10];
  const float* W_fh2 = (const float*)d_in[11];
  const float* W_fh3 = (const float*)d_in[12];
  const int* idd = (const int*)d_in[13];
  const int* idr = (const int*)d_in[14];
  const int* idl = (const int*)d_in[15];

  const size_t M = 16384;  // B*L
  char* p = (char*)d_ws;
  u16* AF = (u16*)p;    p += M * 3072 * 2;            // 96MB
  u16* Ac = (u16*)p;    p += M * 3072 * 2;            // 96MB
  u16* IOUc = (u16*)p;  p += M * 3072 * 2;            // 96MB
  u16* WIOUT = (u16*)p; p += (size_t)3072 * 3072 * 2; // 18MB
  u16* WFT = (u16*)p;   p += (size_t)1024 * 3072 * 2; // 6MB
  u16* F = (u16*)p;     p += M * 1024 * 2;            // 32MB
  int* updated = (int*)p; p += M * 4;
  int* cidx = (int*)p;    p += M * 4;
  int* mc = (int*)p;      p += 64;

  float* outh = (float*)d_out;
  float* outc = outh + M * 1024;

  idx_kernel<<<1, 1024, 0, stream>>>(idd, updated, cidx, mc);
  prep_kernel<<<dim3(512, 32), 256, 0, stream>>>(x, h0, idd, idr, idl,
                                                 updated, cidx, AF, Ac);
  packw_kernel<<<6144, 256, 0, stream>>>(W_ioux, W_iouh_r, W_iouh_l, W_fx,
                                         W_fh0, W_fh1, W_fh2, W_fh3, WIOUT,
                                         WFT);
  gemm_m<<<1024, 512, 0, stream>>>(AF, WFT, F, b_fx, Ac, WIOUT, IOUc, b_ioux,
                                   mc);
  epi_kernel<<<dim3(512, 32), 256, 0, stream>>>(IOUc, F, h0, c0, idd, updated,
                                                cidx, outh, outc);
}

// Round 14
// 486.241 us; speedup vs baseline: 1.0352x; 1.0352x over previous
//
#include <hip/hip_runtime.h>
#include <hip/hip_bf16.h>

typedef unsigned short u16;
typedef unsigned int u32;
typedef unsigned long long u64;
typedef float f32x4 __attribute__((ext_vector_type(4)));
typedef u16 u16x4 __attribute__((ext_vector_type(4)));
typedef u16 u16x8 __attribute__((ext_vector_type(8)));
typedef short s16x8 __attribute__((ext_vector_type(8)));

// ---------- helpers ----------
__device__ __forceinline__ u16 f2b(float f) {
  return __builtin_bit_cast(u16, __float2bfloat16(f));
}
__device__ __forceinline__ float b2f(u16 u) {
  return __builtin_bit_cast(float, ((u32)u) << 16);
}
__device__ __forceinline__ f32x4 ldb4(const u16* __restrict__ p) {
  u16x4 v = *(const u16x4*)p;
  f32x4 r;
#pragma unroll
  for (int i = 0; i < 4; ++i) r[i] = b2f(v[i]);
  return r;
}
__device__ __forceinline__ u16x4 cvt4(f32x4 v) {
  u16x4 r;
#pragma unroll
  for (int i = 0; i < 4; ++i) r[i] = f2b(v[i]);
  return r;
}
__device__ __forceinline__ f32x4 sigm4(f32x4 x) {
  f32x4 r;
#pragma unroll
  for (int i = 0; i < 4; ++i) r[i] = 1.0f / (1.0f + __expf(-x[i]));
  return r;
}
__device__ __forceinline__ f32x4 tanh4(f32x4 x) {
  f32x4 r;
#pragma unroll
  for (int i = 0; i < 4; ++i) {
    float xx = fminf(fmaxf(x[i], -15.0f), 15.0f);
    float e = __expf(2.0f * xx);
    r[i] = (e - 1.0f) / (e + 1.0f);
  }
  return r;
}

__device__ __forceinline__ void gload_lds16(const void* g, void* l) {
  typedef __attribute__((address_space(1))) const u32 gq_t;
  typedef __attribute__((address_space(3))) u32 lq_t;
  gq_t* gp = (gq_t*)(u64)(size_t)g;
  lq_t* lp = (lq_t*)(u32)(size_t)l;
  __builtin_amdgcn_global_load_lds(gp, lp, 16, 0, 0);
}

__device__ __forceinline__ f32x4 mfma_b(u16x8 a, u16x8 b, f32x4 c) {
  return __builtin_amdgcn_mfma_f32_16x16x32_bf16(
      __builtin_bit_cast(s16x8, a), __builtin_bit_cast(s16x8, b), c, 0, 0, 0);
}

// ---------- kernel 1: flags — updated[j] = (exists l: idd[l]==j) && j!=0 ----
__global__ __launch_bounds__(512) void flags_kernel(
    const int* __restrict__ idd, int* __restrict__ updated) {
  __shared__ int sf[512];
  const int b = blockIdx.x;
  const int l = threadIdx.x;
  sf[l] = 0;
  __syncthreads();
  const int id = idd[(size_t)b * 512 + l];
  sf[id] = 1;  // benign same-value race
  __syncthreads();
  updated[(size_t)b * 512 + l] = (l != 0) ? sf[l] : 0;
}

// ---------- kernel 2: compact — cidx (compact index per updated row), mc ---
__global__ __launch_bounds__(1024) void compact_kernel(
    const int* __restrict__ updated, int* __restrict__ cidx,
    int* __restrict__ mc) {
  __shared__ int sc[1024];
  const int t = threadIdx.x;
  int fl[16];
  int cl = 0;
#pragma unroll
  for (int i = 0; i < 16; ++i) {
    fl[i] = updated[t * 16 + i];
    cl += fl[i];
  }
  sc[t] = cl;
  __syncthreads();
  for (int d = 1; d < 1024; d <<= 1) {
    int v = sc[t];
    int add = (t >= d) ? sc[t - d] : 0;
    __syncthreads();
    sc[t] = v + add;
    __syncthreads();
  }
  int pos = sc[t] - cl;  // exclusive prefix
#pragma unroll
  for (int i = 0; i < 16; ++i)
    if (fl[i]) cidx[t * 16 + i] = pos++;
  if (t == 1023) mc[0] = sc[1023];
}

// ---------- kernel 3: prep ----------
// Always: AF[grow][3072] = [bf16(x[d]) | bf16(h0[dr]) | bf16(h0[dl])].
// If updated: Ac[cidx[grow]][3072] = [bf16(x[grow]) | HR | HL] (compacted),
// where HR/HL are the dr/dl scatter-aggregates of h0 rows.
__global__ __launch_bounds__(256) void prep_kernel(
    const float* __restrict__ x, const float* __restrict__ h0,
    const int* __restrict__ idd, const int* __restrict__ idr,
    const int* __restrict__ idl, const int* __restrict__ updated,
    const int* __restrict__ cidx, u16* __restrict__ AF, u16* __restrict__ Ac) {
  __shared__ int listR[512], listL[512];
  __shared__ int cnt[2];
  const int j = blockIdx.x;
  const int b = blockIdx.y;
  const int tid = threadIdx.x;
  const int lane = tid & 63;
  const int wave = tid >> 6;
  const size_t grow = (size_t)b * 512 + j;
  const size_t bbase = (size_t)b * 512;
  const int k = tid * 4;

  // AF gather (every row)
  const int dd = idd[grow], rr = idr[grow], ll = idl[grow];
  u16* ar = AF + grow * 3072;
  *(u16x4*)(ar + k) = cvt4(*(const f32x4*)(x + (bbase + dd) * 1024 + k));
  *(u16x4*)(ar + 1024 + k) =
      cvt4(*(const f32x4*)(h0 + (bbase + rr) * 1024 + k));
  *(u16x4*)(ar + 2048 + k) =
      cvt4(*(const f32x4*)(h0 + (bbase + ll) * 1024 + k));

  if (!updated[grow]) return;  // block-uniform

  if (wave == 1 || wave == 2) {
    const int* ids = (wave == 1 ? idr : idl) + bbase;
    int* lst = (wave == 1 ? listR : listL);
    int base = 0;
#pragma unroll
    for (int c2 = 0; c2 < 8; ++c2) {
      int l = c2 * 64 + lane;
      int id = ids[l];
      u64 m = __ballot(id == j);
      if (id == j) {
        int pos = __popcll(m & ((1ull << lane) - 1ull));
        lst[base + pos] = l;
      }
      base += __popcll(m);
    }
    if (lane == 0) cnt[wave - 1] = base;
  }
  __syncthreads();

  u16* cr = Ac + (size_t)cidx[grow] * 3072;
  *(u16x4*)(cr + k) = cvt4(*(const f32x4*)(x + grow * 1024 + k));

  f32x4 sr = {0.f, 0.f, 0.f, 0.f};
  for (int t = 0; t < cnt[0]; ++t)
    sr += *(const f32x4*)(h0 + (bbase + listR[t]) * 1024 + k);
  *(u16x4*)(cr + 1024 + k) = cvt4(sr);

  f32x4 sl = {0.f, 0.f, 0.f, 0.f};
  for (int t = 0; t < cnt[1]; ++t)
    sl += *(const f32x4*)(h0 + (bbase + listL[t]) * 1024 + k);
  *(u16x4*)(cr + 2048 + k) = cvt4(sl);
}

// ---------- kernel 4: pack weights: WIOUT[3072][3072], WFT[1024][3072] -----
__global__ __launch_bounds__(256) void packw_kernel(
    const float* __restrict__ W_ioux, const float* __restrict__ W_iouh_r,
    const float* __restrict__ W_iouh_l, const float* __restrict__ W_fx,
    const float* __restrict__ W_fh0, const float* __restrict__ W_fh1,
    const float* __restrict__ W_fh2, const float* __restrict__ W_fh3,
    u16* __restrict__ WIOUT, u16* __restrict__ WFT) {
  const int t = blockIdx.x * 256 + threadIdx.x;
  const int NIOU = 3072 * 384;
  float v[8];
  if (t < NIOU) {
    const int n = t % 3072;
    const int k0 = (t / 3072) * 8;
    if (k0 < 1024) {
#pragma unroll
      for (int i = 0; i < 8; ++i) v[i] = W_ioux[(size_t)(k0 + i) * 3072 + n];
    } else if (k0 < 2048) {
#pragma unroll
      for (int i = 0; i < 8; ++i) v[i] = W_iouh_r[(size_t)(k0 - 1024 + i) * 3072 + n];
    } else {
#pragma unroll
      for (int i = 0; i < 8; ++i) v[i] = W_iouh_l[(size_t)(k0 - 2048 + i) * 3072 + n];
    }
    u16x8 o;
#pragma unroll
    for (int i = 0; i < 8; ++i) o[i] = f2b(v[i]);
    *(u16x8*)(WIOUT + (size_t)n * 3072 + k0) = o;
  } else {
    const int u = t - NIOU;
    const int n = u & 1023;
    const int k0 = (u >> 10) * 8;
    if (k0 < 1024) {
#pragma unroll
      for (int i = 0; i < 8; ++i) v[i] = W_fx[(size_t)(k0 + i) * 1024 + n];
    } else if (k0 < 2048) {
#pragma unroll
      for (int i = 0; i < 8; ++i)
        v[i] = W_fh0[(size_t)(k0 - 1024 + i) * 1024 + n] +
               W_fh1[(size_t)(k0 - 1024 + i) * 1024 + n];
    } else {
#pragma unroll
      for (int i = 0; i < 8; ++i)
        v[i] = W_fh2[(size_t)(k0 - 2048 + i) * 1024 + n] +
               W_fh3[(size_t)(k0 - 2048 + i) * 1024 + n];
    }
    u16x8 o;
#pragma unroll
    for (int i = 0; i < 8; ++i) o[i] = f2b(v[i]);
    *(u16x8*)(WFT + (size_t)n * 3072 + k0) = o;
  }
}

// ---------- kernel 5: merged 256x256 NT GEMM (champion schedule) -----------
// Grid 1024: bid<256 -> F role (AF @ WFT^T + b_fx -> F, N=1024);
// else IOU role (Ac @ WIOUT^T + b_ioux -> IOUc compact rows, N=3072,
// early-exit past McPad). A and B strides are 3072 for both -> one code path.
#define BARRIER __builtin_amdgcn_s_barrier()
#define VMCNT(n) asm volatile("s_waitcnt vmcnt(" #n ")")

__global__ __launch_bounds__(512, 2) void gemm_m(
    const u16* __restrict__ AF, const u16* __restrict__ WFT,
    u16* __restrict__ F, const float* __restrict__ bfx,
    const u16* __restrict__ Ac, const u16* __restrict__ WIOUT,
    u16* __restrict__ IOUc, const float* __restrict__ biou,
    const int* __restrict__ mc) {
  const int nk = 48;  // K = 3072
  __shared__ u16 lds_u16[65536];  // 128 KB: A 2x32KB @0, B 2x32KB @65536
  char* ldsb = (char*)lds_u16;
  const int tid = threadIdx.x;
  const int lane = tid & 63;
  const int wave = tid >> 6;
  const int wm = wave >> 2, wn = wave & 3;

  const int bid = blockIdx.x;
  const bool isF = bid < 256;
  const int lb = isF ? bid : bid - 256;
  const int nwg = isF ? 256 : 768;
  const int nbn = isF ? 4 : 12;
  const int swz = (lb & 7) * (nwg >> 3) + (lb >> 3);
  const int bm = swz / nbn, bn = swz % nbn;

  if (!isF) {
    const int McPad = (mc[0] + 255) & ~255;
    if (bm * 256 >= McPad) return;
  }

  const int N = isF ? 1024 : 3072;
  const u16* Abase = isF ? AF : Ac;
  const u16* Bt = isF ? WFT : WIOUT;
  u16* C = isF ? F : IOUc;
  const float* bias = isF ? bfx : biou;

  // staging source: inverse-XOR-swizzled so swizzled ds_reads see linear data
  const int srow = tid >> 3;
  const int ssw = (((tid & 7) * 16) ^ ((srow & 7) << 4)) >> 1;
  const u16* Ab = Abase + (size_t)(bm * 256 + srow) * 3072 + ssw;
  const u16* Bb = Bt + (size_t)(bn * 256 + srow) * 3072 + ssw;

#define SAg(PB, c, kt)                                                \
  gload_lds16(Ab + (size_t)(c) * 64 * 3072 + (size_t)(kt) * 64,       \
              ldsb + (PB) + (c) * 8192 + tid * 16)
#define SBg(PB, c, kt)                                                \
  gload_lds16(Bb + (size_t)(c) * 64 * 3072 + (size_t)(kt) * 64,       \
              ldsb + 65536 + (PB) + (c) * 8192 + tid * 16)

  // fragment read offsets (XOR swizzle depends only on lane)
  const int lb15 = lane & 15;
  const int lh16 = (lane >> 4) * 16;
  const int sw = (lane & 7) << 4;
  int a_off[2], b_off[2];
  a_off[0] = (wm * 64 + lb15) * 128 + (lh16 ^ sw);
  a_off[1] = (wm * 64 + lb15) * 128 + ((64 + lh16) ^ sw);
  b_off[0] = 65536 + (wn * 32 + lb15) * 128 + (lh16 ^ sw);
  b_off[1] = 65536 + (wn * 32 + lb15) * 128 + ((64 + lh16) ^ sw);

#define LDA(AR, PB, MS)                                                    \
  _Pragma("unroll") for (int fm = 0; fm < 4; ++fm) _Pragma("unroll")       \
      for (int kk = 0; kk < 2; ++kk) AR[fm][kk] =                          \
          *(const u16x8*)(ldsb + (PB) + a_off[kk] + (MS)*16384 + fm * 2048)
#define LDB(BR, PB, NS)                                                    \
  _Pragma("unroll") for (int fn = 0; fn < 2; ++fn) _Pragma("unroll")       \
      for (int kk = 0; kk < 2; ++kk) BR[fn][kk] =                          \
          *(const u16x8*)(ldsb + (PB) + b_off[kk] + (NS)*16384 + fn * 2048)
#define MFMAQ(MS, NS, AR, BR)                                              \
  _Pragma("unroll") for (int kk = 0; kk < 2; ++kk) _Pragma("unroll")       \
      for (int fm = 0; fm < 4; ++fm) _Pragma("unroll")                     \
      for (int fn = 0; fn < 2; ++fn) acc[MS][fm][NS][fn] =                 \
          mfma_b(AR[fm][kk], BR[fn][kk], acc[MS][fm][NS][fn])

  u16x8 ar0[4][2], ar1[4][2], br0[2][2], br1[2][2];
  f32x4 acc[2][4][2][2] = {};

  // prologue: tile0 all 8 chunks -> buf0; tile1's A01,B23 -> buf1
  SAg(0, 0, 0); SAg(0, 1, 0); SAg(0, 2, 0); SAg(0, 3, 0);
  SBg(0, 0, 0); SBg(0, 1, 0); SBg(0, 2, 0); SBg(0, 3, 0);
  SAg(32768, 0, 1); SAg(32768, 1, 1);
  SBg(32768, 2, 1); SBg(32768, 3, 1);
  VMCNT(4);
  BARRIER;

#define TILEBODY(PB, QB, Tcur)                                          \
  {                                                                     \
    const int s1 = ((Tcur) + 1 < nk) ? (Tcur) + 1 : nk - 1;             \
    const int s2 = ((Tcur) + 2 < nk) ? (Tcur) + 2 : nk - 1;             \
    SAg(QB, 2, s1); SAg(QB, 3, s1);                                     \
    LDB(br0, PB, 0);                                                    \
    LDA(ar0, PB, 0);                                                    \
    __builtin_amdgcn_s_setprio(1);                                      \
    MFMAQ(0, 0, ar0, br0);                                              \
    __builtin_amdgcn_s_setprio(0);                                      \
    BARRIER;                                                            \
    SBg(QB, 0, s1); SBg(QB, 1, s1);                                     \
    LDB(br1, PB, 1);                                                    \
    __builtin_amdgcn_s_setprio(1);                                      \
    MFMAQ(0, 1, ar0, br1);                                              \
    __builtin_amdgcn_s_setprio(0);                                      \
    BARRIER;                                                            \
    SAg(PB, 0, s2); SAg(PB, 1, s2);                                     \
    LDA(ar1, PB, 1);                                                    \
    __builtin_amdgcn_s_setprio(1);                                      \
    MFMAQ(1, 1, ar1, br1);                                              \
    __builtin_amdgcn_s_setprio(0);                                      \
    BARRIER;                                                            \
    SBg(PB, 2, s2); SBg(PB, 3, s2);                                     \
    __builtin_amdgcn_s_setprio(1);                                      \
    MFMAQ(1, 0, ar1, br0);                                              \
    __builtin_amdgcn_s_setprio(0);                                      \
    VMCNT(4);                                                           \
    BARRIER;                                                            \
  }

  for (int T = 0; T < nk; T += 2) {
    TILEBODY(0, 32768, T);
    TILEBODY(32768, 0, T + 1);
  }
  VMCNT(0);

  // epilogue
#pragma unroll
  for (int ms = 0; ms < 2; ++ms)
#pragma unroll
    for (int fm = 0; fm < 4; ++fm) {
      const int row0 = bm * 256 + ms * 128 + wm * 64 + fm * 16 + ((lane >> 4) * 4);
#pragma unroll
      for (int ns = 0; ns < 2; ++ns)
#pragma unroll
        for (int fn = 0; fn < 2; ++fn) {
          const int col = bn * 256 + ns * 128 + wn * 32 + fn * 16 + lb15;
          const float bv = bias[col];
#pragma unroll
          for (int r = 0; r < 4; ++r)
            C[(size_t)(row0 + r) * N + col] = f2b(acc[ms][fm][ns][fn][r] + bv);
        }
    }
#undef SAg
#undef SBg
#undef LDA
#undef LDB
#undef MFMAQ
#undef TILEBODY
}

// ---------- kernel 6: epilogue — gates + fc scatter (D-list only) ----------
__global__ __launch_bounds__(256) void epi_kernel(
    const u16* __restrict__ IOUc, const u16* __restrict__ F,
    const float* __restrict__ h0, const float* __restrict__ c0,
    const int* __restrict__ idd, const int* __restrict__ updated,
    const int* __restrict__ cidx, float* __restrict__ outh,
    float* __restrict__ outc) {
  __shared__ int listD[512];
  __shared__ int cnt0;
  const int j = blockIdx.x;
  const int b = blockIdx.y;
  const int tid = threadIdx.x;
  const int lane = tid & 63;
  const int wave = tid >> 6;
  const size_t grow = (size_t)b * 512 + j;
  const int k = tid * 4;

  if (!updated[grow]) {  // not updated: pass through (no ballot needed)
    f32x4 hv = *(const f32x4*)(h0 + grow * 1024 + k);
    f32x4 cv = *(const f32x4*)(c0 + grow * 1024 + k);
    *(f32x4*)(outh + grow * 1024 + k) = hv;
    *(f32x4*)(outc + grow * 1024 + k) = cv;
    return;
  }

  if (wave == 0) {
    const int* ids = idd + (size_t)b * 512;
    int base = 0;
#pragma unroll
    for (int c2 = 0; c2 < 8; ++c2) {
      int l = c2 * 64 + lane;
      int id = ids[l];
      u64 m = __ballot(id == j);
      if (id == j) {
        int pos = __popcll(m & ((1ull << lane) - 1ull));
        listD[base + pos] = l;
      }
      base += __popcll(m);
    }
    if (lane == 0) cnt0 = base;
  }
  __syncthreads();

  const int nD = cnt0;
  const u16* io = IOUc + (size_t)cidx[grow] * 3072;
  f32x4 gi = sigm4(ldb4(io + k));
  f32x4 go = sigm4(ldb4(io + 1024 + k));
  f32x4 gu = tanh4(ldb4(io + 2048 + k));
  f32x4 c = gi * gu;
  for (int t = 0; t < nD; ++t) {
    const size_t crow = (size_t)b * 512 + listD[t];
    f32x4 fg = sigm4(ldb4(F + crow * 1024 + k));  // b_fx folded in GEMM
    f32x4 cc = *(const f32x4*)(c0 + crow * 1024 + k);
    c += fg * cc;
  }
  f32x4 h = go * tanh4(c);
  *(f32x4*)(outh + grow * 1024 + k) = h;
  *(f32x4*)(outc + grow * 1024 + k) = c;
}

// ---------- host ----------
extern "C" void kernel_launch(void* const* d_in, const int* in_sizes, int n_in,
                              void* d_out, int out_size, void* d_ws,
                              size_t ws_size, hipStream_t stream) {
  const float* x = (const float*)d_in[0];
  const float* h0 = (const float*)d_in[1];
  const float* c0 = (const float*)d_in[2];
  const float* W_ioux = (const float*)d_in[3];
  const float* b_ioux = (const float*)d_in[4];
  const float* W_iouh_r = (const float*)d_in[5];
  const float* W_iouh_l = (const float*)d_in[6];
  const float* W_fx = (const float*)d_in[7];
  const float* b_fx = (const float*)d_in[8];
  const float* W_fh0 = (const float*)d_in[9];
  const float* W_fh1 = (const float*)d_in[10];
  const float* W_fh2 = (const float*)d_in[11];
  const float* W_fh3 = (const float*)d_in[12];
  const int* idd = (const int*)d_in[13];
  const int* idr = (const int*)d_in[14];
  const int* idl = (const int*)d_in[15];

  const size_t M = 16384;  // B*L
  char* p = (char*)d_ws;
  u16* AF = (u16*)p;    p += M * 3072 * 2;            // 96MB
  u16* Ac = (u16*)p;    p += M * 3072 * 2;            // 96MB
  u16* IOUc = (u16*)p;  p += M * 3072 * 2;            // 96MB
  u16* WIOUT = (u16*)p; p += (size_t)3072 * 3072 * 2; // 18MB
  u16* WFT = (u16*)p;   p += (size_t)1024 * 3072 * 2; // 6MB
  u16* F = (u16*)p;     p += M * 1024 * 2;            // 32MB
  int* updated = (int*)p; p += M * 4;
  int* cidx = (int*)p;    p += M * 4;
  int* mc = (int*)p;      p += 64;

  float* outh = (float*)d_out;
  float* outc = outh + M * 1024;

  flags_kernel<<<32, 512, 0, stream>>>(idd, updated);
  compact_kernel<<<1, 1024, 0, stream>>>(updated, cidx, mc);
  prep_kernel<<<dim3(512, 32), 256, 0, stream>>>(x, h0, idd, idr, idl,
                                                 updated, cidx, AF, Ac);
  packw_kernel<<<6144, 256, 0, stream>>>(W_ioux, W_iouh_r, W_iouh_l, W_fx,
                                         W_fh0, W_fh1, W_fh2, W_fh3, WIOUT,
                                         WFT);
  gemm_m<<<1024, 512, 0, stream>>>(AF, WFT, F, b_fx, Ac, WIOUT, IOUc, b_ioux,
                                   mc);
  epi_kernel<<<dim3(512, 32), 256, 0, stream>>>(IOUc, F, h0, c0, idd, updated,
                                                cidx, outh, outc);
}

// Round 15
// 483.972 us; speedup vs baseline: 1.0400x; 1.0047x over previous
//
#include <hip/hip_runtime.h>
#include <hip/hip_bf16.h>

typedef unsigned short u16;
typedef unsigned int u32;
typedef unsigned long long u64;
typedef float f32x4 __attribute__((ext_vector_type(4)));
typedef u16 u16x4 __attribute__((ext_vector_type(4)));
typedef u16 u16x8 __attribute__((ext_vector_type(8)));
typedef short s16x8 __attribute__((ext_vector_type(8)));

// ---------- helpers ----------
__device__ __forceinline__ u16 f2b(float f) {
  return __builtin_bit_cast(u16, __float2bfloat16(f));
}
__device__ __forceinline__ float b2f(u16 u) {
  return __builtin_bit_cast(float, ((u32)u) << 16);
}
__device__ __forceinline__ f32x4 ldb4(const u16* __restrict__ p) {
  u16x4 v = *(const u16x4*)p;
  f32x4 r;
#pragma unroll
  for (int i = 0; i < 4; ++i) r[i] = b2f(v[i]);
  return r;
}
__device__ __forceinline__ u16x4 cvt4(f32x4 v) {
  u16x4 r;
#pragma unroll
  for (int i = 0; i < 4; ++i) r[i] = f2b(v[i]);
  return r;
}
__device__ __forceinline__ f32x4 sigm4(f32x4 x) {
  f32x4 r;
#pragma unroll
  for (int i = 0; i < 4; ++i) r[i] = 1.0f / (1.0f + __expf(-x[i]));
  return r;
}
__device__ __forceinline__ f32x4 tanh4(f32x4 x) {
  f32x4 r;
#pragma unroll
  for (int i = 0; i < 4; ++i) {
    float xx = fminf(fmaxf(x[i], -15.0f), 15.0f);
    float e = __expf(2.0f * xx);
    r[i] = (e - 1.0f) / (e + 1.0f);
  }
  return r;
}

__device__ __forceinline__ void gload_lds16(const void* g, void* l) {
  typedef __attribute__((address_space(1))) const u32 gq_t;
  typedef __attribute__((address_space(3))) u32 lq_t;
  gq_t* gp = (gq_t*)(u64)(size_t)g;
  lq_t* lp = (lq_t*)(u32)(size_t)l;
  __builtin_amdgcn_global_load_lds(gp, lp, 16, 0, 0);
}

__device__ __forceinline__ f32x4 mfma_b(u16x8 a, u16x8 b, f32x4 c) {
  return __builtin_amdgcn_mfma_f32_16x16x32_bf16(
      __builtin_bit_cast(s16x8, a), __builtin_bit_cast(s16x8, b), c, 0, 0, 0);
}

// ---------- kernel 1: flags — updated[j] = (exists l: idd[l]==j) && j!=0 ----
__global__ __launch_bounds__(512) void flags_kernel(
    const int* __restrict__ idd, int* __restrict__ updated) {
  __shared__ int sf[512];
  const int b = blockIdx.x;
  const int l = threadIdx.x;
  sf[l] = 0;
  __syncthreads();
  const int id = idd[(size_t)b * 512 + l];
  sf[id] = 1;  // benign same-value race
  __syncthreads();
  updated[(size_t)b * 512 + l] = (l != 0) ? sf[l] : 0;
}

// ---------- kernel 2: compact — cidx (compact index per updated row), mc ---
__global__ __launch_bounds__(1024) void compact_kernel(
    const int* __restrict__ updated, int* __restrict__ cidx,
    int* __restrict__ mc) {
  __shared__ int sc[1024];
  const int t = threadIdx.x;
  int fl[16];
  int cl = 0;
#pragma unroll
  for (int i = 0; i < 16; ++i) {
    fl[i] = updated[t * 16 + i];
    cl += fl[i];
  }
  sc[t] = cl;
  __syncthreads();
  for (int d = 1; d < 1024; d <<= 1) {
    int v = sc[t];
    int add = (t >= d) ? sc[t - d] : 0;
    __syncthreads();
    sc[t] = v + add;
    __syncthreads();
  }
  int pos = sc[t] - cl;  // exclusive prefix
#pragma unroll
  for (int i = 0; i < 16; ++i)
    if (fl[i]) cidx[t * 16 + i] = pos++;
  if (t == 1023) mc[0] = sc[1023];
}

// ---------- kernel 3: prep ----------
// Always: AF[grow][3072] = [bf16(x[d]) | bf16(h0[dr]) | bf16(h0[dl])].
// If updated: Ac[cidx[grow]][3072] = [bf16(x[grow]) | HR | HL] (compacted),
// where HR/HL are the dr/dl scatter-aggregates of h0 rows.
__global__ __launch_bounds__(256) void prep_kernel(
    const float* __restrict__ x, const float* __restrict__ h0,
    const int* __restrict__ idd, const int* __restrict__ idr,
    const int* __restrict__ idl, const int* __restrict__ updated,
    const int* __restrict__ cidx, u16* __restrict__ AF, u16* __restrict__ Ac) {
  __shared__ int listR[512], listL[512];
  __shared__ int cnt[2];
  const int j = blockIdx.x;
  const int b = blockIdx.y;
  const int tid = threadIdx.x;
  const int lane = tid & 63;
  const int wave = tid >> 6;
  const size_t grow = (size_t)b * 512 + j;
  const size_t bbase = (size_t)b * 512;
  const int k = tid * 4;

  // AF gather (every row)
  const int dd = idd[grow], rr = idr[grow], ll = idl[grow];
  u16* ar = AF + grow * 3072;
  *(u16x4*)(ar + k) = cvt4(*(const f32x4*)(x + (bbase + dd) * 1024 + k));
  *(u16x4*)(ar + 1024 + k) =
      cvt4(*(const f32x4*)(h0 + (bbase + rr) * 1024 + k));
  *(u16x4*)(ar + 2048 + k) =
      cvt4(*(const f32x4*)(h0 + (bbase + ll) * 1024 + k));

  if (!updated[grow]) return;  // block-uniform

  if (wave == 1 || wave == 2) {
    const int* ids = (wave == 1 ? idr : idl) + bbase;
    int* lst = (wave == 1 ? listR : listL);
    int base = 0;
#pragma unroll
    for (int c2 = 0; c2 < 8; ++c2) {
      int l = c2 * 64 + lane;
      int id = ids[l];
      u64 m = __ballot(id == j);
      if (id == j) {
        int pos = __popcll(m & ((1ull << lane) - 1ull));
        lst[base + pos] = l;
      }
      base += __popcll(m);
    }
    if (lane == 0) cnt[wave - 1] = base;
  }
  __syncthreads();

  u16* cr = Ac + (size_t)cidx[grow] * 3072;
  *(u16x4*)(cr + k) = cvt4(*(const f32x4*)(x + grow * 1024 + k));

  f32x4 sr = {0.f, 0.f, 0.f, 0.f};
  for (int t = 0; t < cnt[0]; ++t)
    sr += *(const f32x4*)(h0 + (bbase + listR[t]) * 1024 + k);
  *(u16x4*)(cr + 1024 + k) = cvt4(sr);

  f32x4 sl = {0.f, 0.f, 0.f, 0.f};
  for (int t = 0; t < cnt[1]; ++t)
    sl += *(const f32x4*)(h0 + (bbase + listL[t]) * 1024 + k);
  *(u16x4*)(cr + 2048 + k) = cvt4(sl);
}

// ---------- kernel 4: pack weights: WIOUT[3072][3072], WFT[1024][3072] -----
__global__ __launch_bounds__(256) void packw_kernel(
    const float* __restrict__ W_ioux, const float* __restrict__ W_iouh_r,
    const float* __restrict__ W_iouh_l, const float* __restrict__ W_fx,
    const float* __restrict__ W_fh0, const float* __restrict__ W_fh1,
    const float* __restrict__ W_fh2, const float* __restrict__ W_fh3,
    u16* __restrict__ WIOUT, u16* __restrict__ WFT) {
  const int t = blockIdx.x * 256 + threadIdx.x;
  const int NIOU = 3072 * 384;
  float v[8];
  if (t < NIOU) {
    const int n = t % 3072;
    const int k0 = (t / 3072) * 8;
    if (k0 < 1024) {
#pragma unroll
      for (int i = 0; i < 8; ++i) v[i] = W_ioux[(size_t)(k0 + i) * 3072 + n];
    } else if (k0 < 2048) {
#pragma unroll
      for (int i = 0; i < 8; ++i) v[i] = W_iouh_r[(size_t)(k0 - 1024 + i) * 3072 + n];
    } else {
#pragma unroll
      for (int i = 0; i < 8; ++i) v[i] = W_iouh_l[(size_t)(k0 - 2048 + i) * 3072 + n];
    }
    u16x8 o;
#pragma unroll
    for (int i = 0; i < 8; ++i) o[i] = f2b(v[i]);
    *(u16x8*)(WIOUT + (size_t)n * 3072 + k0) = o;
  } else {
    const int u = t - NIOU;
    const int n = u & 1023;
    const int k0 = (u >> 10) * 8;
    if (k0 < 1024) {
#pragma unroll
      for (int i = 0; i < 8; ++i) v[i] = W_fx[(size_t)(k0 + i) * 1024 + n];
    } else if (k0 < 2048) {
#pragma unroll
      for (int i = 0; i < 8; ++i)
        v[i] = W_fh0[(size_t)(k0 - 1024 + i) * 1024 + n] +
               W_fh1[(size_t)(k0 - 1024 + i) * 1024 + n];
    } else {
#pragma unroll
      for (int i = 0; i < 8; ++i)
        v[i] = W_fh2[(size_t)(k0 - 2048 + i) * 1024 + n] +
               W_fh3[(size_t)(k0 - 2048 + i) * 1024 + n];
    }
    u16x8 o;
#pragma unroll
    for (int i = 0; i < 8; ++i) o[i] = f2b(v[i]);
    *(u16x8*)(WFT + (size_t)n * 3072 + k0) = o;
  }
}

// ---------- kernel 5: merged 256x256 NT GEMM, read-ahead phases ------------
// Grid 1024: bid<256 -> F role (AF @ WFT^T + b_fx -> F, N=1024);
// else IOU role (Ac @ WIOUT^T + b_ioux -> IOUc compact rows, N=3072,
// early-exit past McPad). Quadrant ds_reads are issued one phase BEFORE
// their consuming MFMA (plain C++ reads + builtin MFMA: compiler inserts
// minimal counted lgkm waits, so reads drain UNDER the previous MFMA
// cluster). Region/staging/vmcnt protocol identical to R14 (hazard audit:
// every region has >=2 barriers between read-certification and overwrite).
#define BARRIER __builtin_amdgcn_s_barrier()
#define VMCNT(n) asm volatile("s_waitcnt vmcnt(" #n ")")

__global__ __launch_bounds__(512, 2) void gemm_m(
    const u16* __restrict__ AF, const u16* __restrict__ WFT,
    u16* __restrict__ F, const float* __restrict__ bfx,
    const u16* __restrict__ Ac, const u16* __restrict__ WIOUT,
    u16* __restrict__ IOUc, const float* __restrict__ biou,
    const int* __restrict__ mc) {
  const int nk = 48;  // K = 3072
  __shared__ u16 lds_u16[65536];  // 128 KB: A 2x32KB @0, B 2x32KB @65536
  char* ldsb = (char*)lds_u16;
  const int tid = threadIdx.x;
  const int lane = tid & 63;
  const int wave = tid >> 6;
  const int wm = wave >> 2, wn = wave & 3;

  const int bid = blockIdx.x;
  const bool isF = bid < 256;
  const int lb = isF ? bid : bid - 256;
  const int nwg = isF ? 256 : 768;
  const int nbn = isF ? 4 : 12;
  const int swz = (lb & 7) * (nwg >> 3) + (lb >> 3);
  const int bm = swz / nbn, bn = swz % nbn;

  if (!isF) {
    const int McPad = (mc[0] + 255) & ~255;
    if (bm * 256 >= McPad) return;
  }

  const int N = isF ? 1024 : 3072;
  const u16* Abase = isF ? AF : Ac;
  const u16* Bt = isF ? WFT : WIOUT;
  u16* C = isF ? F : IOUc;
  const float* bias = isF ? bfx : biou;

  // staging source: inverse-XOR-swizzled so swizzled ds_reads see linear data
  const int srow = tid >> 3;
  const int ssw = (((tid & 7) * 16) ^ ((srow & 7) << 4)) >> 1;
  const u16* Ab = Abase + (size_t)(bm * 256 + srow) * 3072 + ssw;
  const u16* Bb = Bt + (size_t)(bn * 256 + srow) * 3072 + ssw;

#define SAg(PB, c, kt)                                                \
  gload_lds16(Ab + (size_t)(c) * 64 * 3072 + (size_t)(kt) * 64,       \
              ldsb + (PB) + (c) * 8192 + tid * 16)
#define SBg(PB, c, kt)                                                \
  gload_lds16(Bb + (size_t)(c) * 64 * 3072 + (size_t)(kt) * 64,       \
              ldsb + 65536 + (PB) + (c) * 8192 + tid * 16)

  // fragment read offsets (XOR swizzle depends only on lane)
  const int lb15 = lane & 15;
  const int lh16 = (lane >> 4) * 16;
  const int sw = (lane & 7) << 4;
  int a_off[2], b_off[2];
  a_off[0] = (wm * 64 + lb15) * 128 + (lh16 ^ sw);
  a_off[1] = (wm * 64 + lb15) * 128 + ((64 + lh16) ^ sw);
  b_off[0] = 65536 + (wn * 32 + lb15) * 128 + (lh16 ^ sw);
  b_off[1] = 65536 + (wn * 32 + lb15) * 128 + ((64 + lh16) ^ sw);

#define LDA(AR, PB, MS)                                                    \
  _Pragma("unroll") for (int fm = 0; fm < 4; ++fm) _Pragma("unroll")       \
      for (int kk = 0; kk < 2; ++kk) AR[fm][kk] =                          \
          *(const u16x8*)(ldsb + (PB) + a_off[kk] + (MS)*16384 + fm * 2048)
#define LDB(BR, PB, NS)                                                    \
  _Pragma("unroll") for (int fn = 0; fn < 2; ++fn) _Pragma("unroll")       \
      for (int kk = 0; kk < 2; ++kk) BR[fn][kk] =                          \
          *(const u16x8*)(ldsb + (PB) + b_off[kk] + (NS)*16384 + fn * 2048)
#define MFMAQ(MS, NS, AR, BR)                                              \
  _Pragma("unroll") for (int kk = 0; kk < 2; ++kk) _Pragma("unroll")       \
      for (int fm = 0; fm < 4; ++fm) _Pragma("unroll")                     \
      for (int fn = 0; fn < 2; ++fn) acc[MS][fm][NS][fn] =                 \
          mfma_b(AR[fm][kk], BR[fn][kk], acc[MS][fm][NS][fn])

  u16x8 ar0[4][2], ar1[4][2], br0[2][2], br1[2][2];
  f32x4 acc[2][4][2][2] = {};

  // prologue: tile0 all 8 chunks -> buf0; tile1's A01,B23 -> buf1
  SAg(0, 0, 0); SAg(0, 1, 0); SAg(0, 2, 0); SAg(0, 3, 0);
  SBg(0, 0, 0); SBg(0, 1, 0); SBg(0, 2, 0); SBg(0, 3, 0);
  SAg(32768, 0, 1); SAg(32768, 1, 1);
  SBg(32768, 2, 1); SBg(32768, 3, 1);
  VMCNT(4);
  BARRIER;

  // TILEBODY (read-ahead): entry reads Q0 frags; each phase issues the NEXT
  // quadrant's reads before its own MFMA, so the reads drain under MFMA.
#define TILEBODY(PB, QB, Tcur)                                          \
  {                                                                     \
    const int s1 = ((Tcur) + 1 < nk) ? (Tcur) + 1 : nk - 1;             \
    const int s2 = ((Tcur) + 2 < nk) ? (Tcur) + 2 : nk - 1;             \
    /* entry: read Q0 operands (br0, ar0) */                            \
    LDB(br0, PB, 0);                                                    \
    LDA(ar0, PB, 0);                                                    \
    /* P1: read br1 (Q1); stage QB A23 (T+1); MFMA Q0 */                \
    LDB(br1, PB, 1);                                                    \
    SAg(QB, 2, s1); SAg(QB, 3, s1);                                     \
    __builtin_amdgcn_s_setprio(1);                                      \
    MFMAQ(0, 0, ar0, br0);                                              \
    __builtin_amdgcn_s_setprio(0);                                      \
    BARRIER;                                                            \
    /* P2: read ar1 (Q2/Q3); stage QB B01 (T+1); MFMA Q1 */             \
    LDA(ar1, PB, 1);                                                    \
    SBg(QB, 0, s1); SBg(QB, 1, s1);                                     \
    __builtin_amdgcn_s_setprio(1);                                      \
    MFMAQ(0, 1, ar0, br1);                                              \
    __builtin_amdgcn_s_setprio(0);                                      \
    BARRIER;                                                            \
    /* P3: stage PB A01 (T+2); MFMA Q2 (regs resident) */               \
    SAg(PB, 0, s2); SAg(PB, 1, s2);                                     \
    __builtin_amdgcn_s_setprio(1);                                      \
    MFMAQ(1, 1, ar1, br1);                                              \
    __builtin_amdgcn_s_setprio(0);                                      \
    BARRIER;                                                            \
    /* P4: stage PB B23 (T+2); MFMA Q3 (regs resident); vmcnt(4) */     \
    SBg(PB, 2, s2); SBg(PB, 3, s2);                                     \
    __builtin_amdgcn_s_setprio(1);                                      \
    MFMAQ(1, 0, ar1, br0);                                              \
    __builtin_amdgcn_s_setprio(0);                                      \
    VMCNT(4);                                                           \
    BARRIER;                                                            \
  }

  for (int T = 0; T < nk; T += 2) {
    TILEBODY(0, 32768, T);
    TILEBODY(32768, 0, T + 1);
  }
  VMCNT(0);

  // epilogue
#pragma unroll
  for (int ms = 0; ms < 2; ++ms)
#pragma unroll
    for (int fm = 0; fm < 4; ++fm) {
      const int row0 = bm * 256 + ms * 128 + wm * 64 + fm * 16 + ((lane >> 4) * 4);
#pragma unroll
      for (int ns = 0; ns < 2; ++ns)
#pragma unroll
        for (int fn = 0; fn < 2; ++fn) {
          const int col = bn * 256 + ns * 128 + wn * 32 + fn * 16 + lb15;
          const float bv = bias[col];
#pragma unroll
          for (int r = 0; r < 4; ++r)
            C[(size_t)(row0 + r) * N + col] = f2b(acc[ms][fm][ns][fn][r] + bv);
        }
    }
#undef SAg
#undef SBg
#undef LDA
#undef LDB
#undef MFMAQ
#undef TILEBODY
}

// ---------- kernel 6: epilogue — gates + fc scatter (D-list only) ----------
__global__ __launch_bounds__(256) void epi_kernel(
    const u16* __restrict__ IOUc, const u16* __restrict__ F,
    const float* __restrict__ h0, const float* __restrict__ c0,
    const int* __restrict__ idd, const int* __restrict__ updated,
    const int* __restrict__ cidx, float* __restrict__ outh,
    float* __restrict__ outc) {
  __shared__ int listD[512];
  __shared__ int cnt0;
  const int j = blockIdx.x;
  const int b = blockIdx.y;
  const int tid = threadIdx.x;
  const int lane = tid & 63;
  const int wave = tid >> 6;
  const size_t grow = (size_t)b * 512 + j;
  const int k = tid * 4;

  if (!updated[grow]) {  // not updated: pass through (no ballot needed)
    f32x4 hv = *(const f32x4*)(h0 + grow * 1024 + k);
    f32x4 cv = *(const f32x4*)(c0 + grow * 1024 + k);
    *(f32x4*)(outh + grow * 1024 + k) = hv;
    *(f32x4*)(outc + grow * 1024 + k) = cv;
    return;
  }

  if (wave == 0) {
    const int* ids = idd + (size_t)b * 512;
    int base = 0;
#pragma unroll
    for (int c2 = 0; c2 < 8; ++c2) {
      int l = c2 * 64 + lane;
      int id = ids[l];
      u64 m = __ballot(id == j);
      if (id == j) {
        int pos = __popcll(m & ((1ull << lane) - 1ull));
        listD[base + pos] = l;
      }
      base += __popcll(m);
    }
    if (lane == 0) cnt0 = base;
  }
  __syncthreads();

  const int nD = cnt0;
  const u16* io = IOUc + (size_t)cidx[grow] * 3072;
  f32x4 gi = sigm4(ldb4(io + k));
  f32x4 go = sigm4(ldb4(io + 1024 + k));
  f32x4 gu = tanh4(ldb4(io + 2048 + k));
  f32x4 c = gi * gu;
  for (int t = 0; t < nD; ++t) {
    const size_t crow = (size_t)b * 512 + listD[t];
    f32x4 fg = sigm4(ldb4(F + crow * 1024 + k));  // b_fx folded in GEMM
    f32x4 cc = *(const f32x4*)(c0 + crow * 1024 + k);
    c += fg * cc;
  }
  f32x4 h = go * tanh4(c);
  *(f32x4*)(outh + grow * 1024 + k) = h;
  *(f32x4*)(outc + grow * 1024 + k) = c;
}

// ---------- host ----------
extern "C" void kernel_launch(void* const* d_in, const int* in_sizes, int n_in,
                              void* d_out, int out_size, void* d_ws,
                              size_t ws_size, hipStream_t stream) {
  const float* x = (const float*)d_in[0];
  const float* h0 = (const float*)d_in[1];
  const float* c0 = (const float*)d_in[2];
  const float* W_ioux = (const float*)d_in[3];
  const float* b_ioux = (const float*)d_in[4];
  const float* W_iouh_r = (const float*)d_in[5];
  const float* W_iouh_l = (const float*)d_in[6];
  const float* W_fx = (const float*)d_in[7];
  const float* b_fx = (const float*)d_in[8];
  const float* W_fh0 = (const float*)d_in[9];
  const float* W_fh1 = (const float*)d_in[10];
  const float* W_fh2 = (const float*)d_in[11];
  const float* W_fh3 = (const float*)d_in[12];
  const int* idd = (const int*)d_in[13];
  const int* idr = (const int*)d_in[14];
  const int* idl = (const int*)d_in[15];

  const size_t M = 16384;  // B*L
  char* p = (char*)d_ws;
  u16* AF = (u16*)p;    p += M * 3072 * 2;            // 96MB
  u16* Ac = (u16*)p;    p += M * 3072 * 2;            // 96MB
  u16* IOUc = (u16*)p;  p += M * 3072 * 2;            // 96MB
  u16* WIOUT = (u16*)p; p += (size_t)3072 * 3072 * 2; // 18MB
  u16* WFT = (u16*)p;   p += (size_t)1024 * 3072 * 2; // 6MB
  u16* F = (u16*)p;     p += M * 1024 * 2;            // 32MB
  int* updated = (int*)p; p += M * 4;
  int* cidx = (int*)p;    p += M * 4;
  int* mc = (int*)p;      p += 64;

  float* outh = (float*)d_out;
  float* outc = outh + M * 1024;

  flags_kernel<<<32, 512, 0, stream>>>(idd, updated);
  compact_kernel<<<1, 1024, 0, stream>>>(updated, cidx, mc);
  prep_kernel<<<dim3(512, 32), 256, 0, stream>>>(x, h0, idd, idr, idl,
                                                 updated, cidx, AF, Ac);
  packw_kernel<<<6144, 256, 0, stream>>>(W_ioux, W_iouh_r, W_iouh_l, W_fx,
                                         W_fh0, W_fh1, W_fh2, W_fh3, WIOUT,
                                         WFT);
  gemm_m<<<1024, 512, 0, stream>>>(AF, WFT, F, b_fx, Ac, WIOUT, IOUc, b_ioux,
                                   mc);
  epi_kernel<<<dim3(512, 32), 256, 0, stream>>>(IOUc, F, h0, c0, idd, updated,
                                                cidx, outh, outc);
}